// Round 7
// baseline (567.420 us; speedup 1.0000x reference)
//
#include <hip/hip_runtime.h>
#include <hip/hip_bf16.h>
#include <hip/hip_cooperative_groups.h>

namespace cg = cooperative_groups;

// ---------------------------------------------------------------------------
// GCN forward, 6-launch pipeline:
//   k_build (cooperative: hist|bscan|sscan|part|fine fused, 4 grid.sync)
//   -> gemm1 (x@W1, MFMA) -> aggF(W2) -> aggF(W3) -> agg3 -> head.
// aggF = R2-structure gather aggregate + fused 16x64 @ 64x64 MFMA epilogue
// producing the NEXT layer's hs (dis-scaled bf16) directly — gemm2/gemm3
// kernels and the obufb round-trip eliminated.
// hs = dis[n]*h[n] bf16 [N+1][64] (+zero dummy row N).
// NOTE (R5): NO float LDS atomics. (R8): don't fuse gather INTO gemm tile
// (reverse direction — gemm into agg epilogue — keeps gather TLP intact).
// NOTE (R10/R11): k_agg not VALU- or issue-latency-bound.
// NOTE (R12/R13/R15): spatial slabs + per-tile chains all lose; k_agg wall =
// dur ~= FETCH/3.5TB/s at 1 line-req/edge with full MLP.
// NOTE (R16): remaining lever was launch count: 13 launches x ~10us gap.
// Build fused via hipLaunchCooperativeKernel (fallback to 5 kernels if
// rejected). k_fine orders each node list by src-tile (N/4 rows) — soft
// temporal phasing for k_agg, numerics-safe (R15), zero structural cost.
// ---------------------------------------------------------------------------

#define NBLK 256        // partition chunks
#define MAXNB 512       // max buckets
#define FCAP 9216       // LDS edge staging in fine phase (36 KB)
#define BPAD 2048       // per-bucket colidx padding slack (256*7 max)
#define SMEMB (FCAP * 4 + 1024 * 4 + 1024 * 4 + 256 * 4)  // 46080 B

typedef __attribute__((ext_vector_type(8))) short short8;
typedef __attribute__((ext_vector_type(4))) float floatx4;
typedef __attribute__((ext_vector_type(2))) float f32x2;

__device__ __forceinline__ float bf2f(unsigned short v) {
    return __uint_as_float(((unsigned int)v) << 16);
}
__device__ __forceinline__ unsigned short f2bf(float x) {
    __hip_bfloat16 b = __float2bfloat16(x);
    return *(unsigned short*)&b;
}
__device__ __forceinline__ void pkacc(f32x2& a, unsigned int u) {
    f32x2 p;
    p.x = __uint_as_float(u << 16);
    p.y = __uint_as_float(u & 0xFFFF0000u);
    asm("v_pk_add_f32 %0, %1, %0" : "+v"(a) : "v"(p));
}
__device__ __forceinline__ void accp(f32x2* a, uint4 u) {
    pkacc(a[0], u.x);
    pkacc(a[1], u.y);
    pkacc(a[2], u.z);
    pkacc(a[3], u.w);
}

// ---------------- build phases as device functions (shared by k_build and
// the non-cooperative fallback wrappers) ----------------

__device__ __forceinline__ void dev_hist(char* smemraw, const int* dst,
                                         int* blockhist, int E, int chunk,
                                         int nb, int b, int t) {
    int* h = (int*)smemraw;
    for (int j = t; j < nb; j += 256) h[j] = 0;
    __syncthreads();
    int lo = b * chunk, hi = min(lo + chunk, E);
    int m = hi - lo;
    if (m < 0) m = 0;
    int nv = m >> 2;
    const int4* d4 = (const int4*)(dst + lo);
    for (int i = t; i < nv; i += 256) {
        int4 v = d4[i];
        atomicAdd(&h[v.x >> 8], 1);
        atomicAdd(&h[v.y >> 8], 1);
        atomicAdd(&h[v.z >> 8], 1);
        atomicAdd(&h[v.w >> 8], 1);
    }
    for (int i = lo + (nv << 2) + t; i < hi; i += 256) atomicAdd(&h[dst[i] >> 8], 1);
    __syncthreads();
    for (int j = t; j < nb; j += 256) blockhist[j * NBLK + b] = h[j];
}

__device__ __forceinline__ void dev_bscan(char* smemraw, int* blockhist,
                                          int* btotal, int j, int t) {
    int* sm = (int*)smemraw;
    int v = blockhist[j * NBLK + t];
    sm[t] = v;
    __syncthreads();
    for (int d = 1; d < 256; d <<= 1) {
        int u = (t >= d) ? sm[t - d] : 0;
        __syncthreads();
        sm[t] += u;
        __syncthreads();
    }
    blockhist[j * NBLK + t] = sm[t] - v;
    if (t == 255) btotal[j] = sm[255];
}

__device__ __forceinline__ void dev_sscan(char* smemraw, const int* btotal,
                                          int* starts, int nb,
                                          unsigned short* z1, unsigned short* z2,
                                          int N, int t) {
    int* sm = (int*)smemraw;
    if (t < 64) {
        z1[(size_t)N * 64 + t] = 0;
        z2[(size_t)N * 64 + t] = 0;
    }
    int base = t * 2;
    int v0 = (base + 0 < nb) ? btotal[base + 0] : 0;
    int v1 = (base + 1 < nb) ? btotal[base + 1] : 0;
    int tsum = v0 + v1;
    sm[t] = tsum;
    __syncthreads();
    for (int d = 1; d < 256; d <<= 1) {
        int u = (t >= d) ? sm[t - d] : 0;
        __syncthreads();
        sm[t] += u;
        __syncthreads();
    }
    int excl = sm[t] - tsum;
    if (base + 0 < nb) starts[base + 0] = excl;
    if (base + 1 < nb) starts[base + 1] = excl + v0;
    if (t == 255) starts[nb] = sm[255];
}

__device__ __forceinline__ void dev_part(char* smemraw, const int* src,
                                         const int* dst, const int* blockhist,
                                         const int* starts, unsigned int* epart,
                                         int E, int chunk, int nb, int b, int t) {
    int* cur = (int*)smemraw;
    for (int j = t; j < nb; j += 256) cur[j] = starts[j] + blockhist[j * NBLK + b];
    __syncthreads();
    int lo = b * chunk, hi = min(lo + chunk, E);
    int m = hi - lo;
    if (m < 0) m = 0;
    int nv = m >> 2;
    const int4* d4 = (const int4*)(dst + lo);
    const int4* s4 = (const int4*)(src + lo);
    for (int i = t; i < nv; i += 256) {
        int4 d = d4[i];
        int4 s = s4[i];
        int p;
        p = atomicAdd(&cur[d.x >> 8], 1); epart[p] = (unsigned int)s.x | ((unsigned int)(d.x & 255) << 17);
        p = atomicAdd(&cur[d.y >> 8], 1); epart[p] = (unsigned int)s.y | ((unsigned int)(d.y & 255) << 17);
        p = atomicAdd(&cur[d.z >> 8], 1); epart[p] = (unsigned int)s.z | ((unsigned int)(d.z & 255) << 17);
        p = atomicAdd(&cur[d.w >> 8], 1); epart[p] = (unsigned int)s.w | ((unsigned int)(d.w & 255) << 17);
    }
    for (int i = lo + (nv << 2) + t; i < hi; i += 256) {
        int d = dst[i];
        int pos = atomicAdd(&cur[d >> 8], 1);
        epart[pos] = (unsigned int)src[i] | ((unsigned int)(d & 255) << 17);
    }
}

// fine: per-bucket per-node lists, ORDERED BY SRC-TILE (4 tiles of TQ rows),
// padded to x8 with dummy row N. colidx stores byte offsets (src<<7).
__device__ __forceinline__ void dev_fine(char* smemraw, const unsigned int* epart,
                                         const int* starts, int* deg, int* rowptr,
                                         float* dis, int* colidx, int N, int TQ,
                                         int j, int t) {
    unsigned int* eb = (unsigned int*)smemraw;           // 36 KB
    int* cnt2 = (int*)(smemraw + FCAP * 4);              // [256][4]
    int* cur2 = cnt2 + 1024;
    int* sc = cur2 + 1024;
    int n0 = j << 8;
    int nn = min(256, N - n0);
    int s = starts[j], e = starts[j + 1];
    int m = e - s;
    int pbase = s + j * BPAD;
    cnt2[t] = 0; cnt2[t + 256] = 0; cnt2[t + 512] = 0; cnt2[t + 768] = 0;
    __syncthreads();
    for (int i = t; i < m; i += 256) {
        unsigned int p = epart[s + i];
        if (i < FCAP) eb[i] = p;
        int tl = (int)(p & 0x1FFFF) / TQ;
        atomicAdd(&cnt2[(int)((p >> 17) << 2) + tl], 1);
    }
    __syncthreads();
    int c0 = cnt2[(t << 2) + 0], c1 = cnt2[(t << 2) + 1];
    int c2 = cnt2[(t << 2) + 2], c3 = cnt2[(t << 2) + 3];
    int cnt = c0 + c1 + c2 + c3;
    int pcv = (cnt + 7) & ~7;
    sc[t] = pcv;
    __syncthreads();
    for (int d = 1; d < 256; d <<= 1) {
        int u = (t >= d) ? sc[t - d] : 0;
        __syncthreads();
        sc[t] += u;
        __syncthreads();
    }
    int rp = pbase + sc[t] - pcv;
    if (t < nn) {
        deg[n0 + t] = cnt;
        rowptr[n0 + t] = rp;
        dis[n0 + t] = rsqrtf((float)cnt + 1.0f);
    }
    cur2[(t << 2) + 0] = rp;
    cur2[(t << 2) + 1] = rp + c0;
    cur2[(t << 2) + 2] = rp + c0 + c1;
    cur2[(t << 2) + 3] = rp + c0 + c1 + c2;
    __syncthreads();
    for (int i = t; i < m; i += 256) {
        unsigned int p = (i < FCAP) ? eb[i] : epart[s + i];
        int srcn = (int)(p & 0x1FFFF);
        int tl = srcn / TQ;
        int pos = atomicAdd(&cur2[(int)((p >> 17) << 2) + tl], 1);
        colidx[pos] = srcn << 7;
    }
    __syncthreads();
    if (t < nn) {
        int endp = rp + pcv;
        for (int q = rp + cnt; q < endp; ++q) colidx[q] = N << 7;  // dummy row
    }
}

// ---------------- cooperative fused build ----------------
__global__ __launch_bounds__(256) void k_build(const int* __restrict__ src,
                                               const int* __restrict__ dst,
                                               int* __restrict__ blockhist,
                                               int* __restrict__ btotal,
                                               int* __restrict__ starts,
                                               unsigned int* __restrict__ epart,
                                               int* __restrict__ deg,
                                               int* __restrict__ rowptr,
                                               float* __restrict__ dis,
                                               int* __restrict__ colidx,
                                               unsigned short* __restrict__ z1,
                                               unsigned short* __restrict__ z2,
                                               int N, int E, int chunk, int nb,
                                               int TQ) {
    __shared__ char smemraw[SMEMB];
    cg::grid_group grid = cg::this_grid();
    int b = blockIdx.x, t = threadIdx.x;
    if (b < NBLK) dev_hist(smemraw, dst, blockhist, E, chunk, nb, b, t);
    grid.sync();
    if (b < nb) dev_bscan(smemraw, blockhist, btotal, b, t);
    grid.sync();
    if (b == 0) dev_sscan(smemraw, btotal, starts, nb, z1, z2, N, t);
    grid.sync();
    if (b < NBLK) dev_part(smemraw, src, dst, blockhist, starts, epart, E, chunk, nb, b, t);
    grid.sync();
    if (b < nb) dev_fine(smemraw, epart, starts, deg, rowptr, dis, colidx, N, TQ, b, t);
}

// ---------------- fallback wrappers (non-cooperative path) ----------------
__global__ __launch_bounds__(256) void k_hist(const int* __restrict__ dst,
                                              int* __restrict__ blockhist,
                                              int E, int chunk, int nb) {
    __shared__ char smemraw[MAXNB * 4];
    dev_hist(smemraw, dst, blockhist, E, chunk, nb, blockIdx.x, threadIdx.x);
}
__global__ __launch_bounds__(256) void k_bscan(int* __restrict__ blockhist,
                                               int* __restrict__ btotal) {
    __shared__ char smemraw[256 * 4];
    dev_bscan(smemraw, blockhist, btotal, blockIdx.x, threadIdx.x);
}
__global__ __launch_bounds__(256) void k_sscan(const int* __restrict__ btotal,
                                               int* __restrict__ starts, int nb,
                                               unsigned short* __restrict__ z1,
                                               unsigned short* __restrict__ z2,
                                               int N) {
    __shared__ char smemraw[256 * 4];
    dev_sscan(smemraw, btotal, starts, nb, z1, z2, N, threadIdx.x);
}
__global__ __launch_bounds__(256) void k_part(const int* __restrict__ src,
                                              const int* __restrict__ dst,
                                              const int* __restrict__ blockhist,
                                              const int* __restrict__ starts,
                                              unsigned int* __restrict__ epart,
                                              int E, int chunk, int nb) {
    __shared__ char smemraw[MAXNB * 4];
    dev_part(smemraw, src, dst, blockhist, starts, epart, E, chunk, nb,
             blockIdx.x, threadIdx.x);
}
__global__ __launch_bounds__(256) void k_fine(const unsigned int* __restrict__ epart,
                                              const int* __restrict__ starts,
                                              int* __restrict__ deg,
                                              int* __restrict__ rowptr,
                                              float* __restrict__ dis,
                                              int* __restrict__ colidx, int N,
                                              int TQ) {
    __shared__ char smemraw[SMEMB];
    dev_fine(smemraw, epart, starts, deg, rowptr, dis, colidx, N, TQ,
             blockIdx.x, threadIdx.x);
}

// ---------------- layer-1 GEMM (fp32 A, K=128) ----------------
template <int K, int ABF16>
__global__ __launch_bounds__(256) void k_gemm_mfma(const void* __restrict__ Ap,
                                                   const float* __restrict__ W,
                                                   const float* __restrict__ dis,
                                                   unsigned short* __restrict__ hs,
                                                   int N) {
    constexpr int AS = K + 8;
    __shared__ unsigned short As[64 * AS];
    __shared__ unsigned short Bt[64 * AS];
    const int tid = threadIdx.x;
    const int r0 = blockIdx.x * 64;

    for (int idx = tid; idx < K * 64; idx += 256) {
        int k = idx >> 6, n = idx & 63;
        Bt[n * AS + k] = f2bf(W[idx]);
    }
    if (ABF16) {
        const unsigned short* A = (const unsigned short*)Ap;
        for (int idx = tid; idx < 64 * (K / 8); idx += 256) {
            int row = idx / (K / 8), c8 = idx % (K / 8);
            int gr = r0 + row;
            uint4 v = (gr < N) ? *(const uint4*)&A[(size_t)gr * K + c8 * 8]
                               : make_uint4(0u, 0u, 0u, 0u);
            *(uint4*)&As[row * AS + c8 * 8] = v;
        }
    } else {
        const float* A = (const float*)Ap;
        for (int idx = tid; idx < 64 * (K / 4); idx += 256) {
            int row = idx / (K / 4), kq = idx % (K / 4);
            int gr = r0 + row;
            float4 a = (gr < N) ? ((const float4*)(A + (size_t)gr * K))[kq]
                                : make_float4(0.f, 0.f, 0.f, 0.f);
            ushort4 v;
            v.x = f2bf(a.x); v.y = f2bf(a.y); v.z = f2bf(a.z); v.w = f2bf(a.w);
            *(ushort4*)&As[row * AS + kq * 4] = v;
        }
    }
    __syncthreads();

    const int w = tid >> 6, lane = tid & 63;
    const int m = lane & 15, quad = lane >> 4;
    floatx4 acc0 = {0.f, 0.f, 0.f, 0.f};
    floatx4 acc1 = {0.f, 0.f, 0.f, 0.f};
    floatx4 acc2 = {0.f, 0.f, 0.f, 0.f};
    floatx4 acc3 = {0.f, 0.f, 0.f, 0.f};
#pragma unroll
    for (int s = 0; s < K / 32; ++s) {
        int ko = s * 32 + quad * 8;
        short8 a  = *(const short8*)&As[(w * 16 + m) * AS + ko];
        short8 b0 = *(const short8*)&Bt[(0 * 16 + m) * AS + ko];
        short8 b1 = *(const short8*)&Bt[(1 * 16 + m) * AS + ko];
        short8 b2 = *(const short8*)&Bt[(2 * 16 + m) * AS + ko];
        short8 b3 = *(const short8*)&Bt[(3 * 16 + m) * AS + ko];
        acc0 = __builtin_amdgcn_mfma_f32_16x16x32_bf16(a, b0, acc0, 0, 0, 0);
        acc1 = __builtin_amdgcn_mfma_f32_16x16x32_bf16(a, b1, acc1, 0, 0, 0);
        acc2 = __builtin_amdgcn_mfma_f32_16x16x32_bf16(a, b2, acc2, 0, 0, 0);
        acc3 = __builtin_amdgcn_mfma_f32_16x16x32_bf16(a, b3, acc3, 0, 0, 0);
    }
#pragma unroll
    for (int r = 0; r < 4; ++r) {
        int gr = r0 + w * 16 + quad * 4 + r;
        if (gr < N) {
            float dn = dis[gr];
            size_t base = (size_t)gr * 64 + m;
            hs[base + 0]  = f2bf(acc0[r] * dn);
            hs[base + 16] = f2bf(acc1[r] * dn);
            hs[base + 32] = f2bf(acc2[r] * dn);
            hs[base + 48] = f2bf(acc3[r] * dn);
        }
    }
}

// ---------------- gather aggregate (+ optional fused next-layer GEMM) ------
// R2 structure: 4 nodes/wave, lane = slot(2b) x eslot-parity(1b) x cq(3b),
// 2-deep pipeline, 1-level butterfly. FUSE: after agg, stage 16x64 bf16
// out-tile in LDS and compute hs_next = dis * (out @ Wn) via 16x16x32 MFMA
// (wave w -> cols w*16..+16, 2 k-steps). Numerics identical to separate gemm.
template <int RELU, int FUSE>
__global__ __launch_bounds__(256) void k_agg(const unsigned short* __restrict__ hs,
                                             const int* __restrict__ rowptr,
                                             const int* __restrict__ deg,
                                             const int* __restrict__ colidx,
                                             const float* __restrict__ dis,
                                             const float* __restrict__ bias,
                                             const float* __restrict__ Wn,
                                             unsigned short* __restrict__ outp,
                                             int N) {
    constexpr int WS = 72;
    __shared__ unsigned short Wt[FUSE ? 64 * WS : 1];
    __shared__ unsigned short Aout[FUSE ? 16 * WS : 1];

    int lane = threadIdx.x & 63;
    int wv = threadIdx.x >> 6;
    int s = lane >> 4;          // node slot 0..3
    int e = (lane >> 3) & 1;    // edge-slot parity
    int cq = lane & 7;          // channel octet
    int node = blockIdx.x * 16 + wv * 4 + s;
    bool valid = node < N;
    int nodec = valid ? node : 0;

    if (FUSE) {
        for (int idx = threadIdx.x; idx < 64 * 64; idx += 256) {
            int k = idx >> 6, c = idx & 63;
            Wt[c * WS + k] = f2bf(Wn[idx]);
        }
        // visibility guaranteed by the __syncthreads before the matmul
    }

    int rp = rowptr[nodec];
    int cnt = valid ? deg[nodec] : 0;
    int pcnt = (cnt + 7) & ~7;
    int wm = pcnt;
    wm = max(wm, __shfl_xor(wm, 16, 64));
    wm = max(wm, __shfl_xor(wm, 32, 64));

    const int* ci = colidx + rp + e;
    const char* hb = (const char*)hs + cq * 16;
    const int DUMMY = N << 7;
    const int mclamp = max(pcnt - 2, 0);

    f32x2 acc[4];
    acc[0] = (f32x2){0.f, 0.f};
    acc[1] = (f32x2){0.f, 0.f};
    acc[2] = (f32x2){0.f, 0.f};
    acc[3] = (f32x2){0.f, 0.f};

    auto LDO = [&](int i, int& o0, int& o1) {
        int r0 = ci[min(i, mclamp)];
        int r1 = ci[min(i + 2, mclamp)];
        o0 = (i + e < pcnt) ? r0 : DUMMY;
        o1 = (i + 2 + e < pcnt) ? r1 : DUMMY;
    };

    if (wm > 0) {
        int a0, a1, b0, b1;
        LDO(0, a0, a1);
        LDO(4, b0, b1);
        uint4 gA0 = *(const uint4*)(hb + a0);
        uint4 gA1 = *(const uint4*)(hb + a1);
        uint4 gB0 = *(const uint4*)(hb + b0);
        uint4 gB1 = *(const uint4*)(hb + b1);
        for (int i = 8; i < wm; i += 8) {
            int c0, c1, d0, d1;
            LDO(i, c0, c1);
            LDO(i + 4, d0, d1);
            accp(acc, gA0);
            accp(acc, gA1);
            gA0 = *(const uint4*)(hb + c0);
            gA1 = *(const uint4*)(hb + c1);
            accp(acc, gB0);
            accp(acc, gB1);
            gB0 = *(const uint4*)(hb + d0);
            gB1 = *(const uint4*)(hb + d1);
        }
        accp(acc, gA0);
        accp(acc, gA1);
        accp(acc, gB0);
        accp(acc, gB1);
    }

#pragma unroll
    for (int q = 0; q < 4; ++q) {
        f32x2 t;
        t.x = __shfl_xor(acc[q].x, 8, 64);
        t.y = __shfl_xor(acc[q].y, 8, 64);
        asm("v_pk_add_f32 %0, %1, %0" : "+v"(acc[q]) : "v"(t));
    }

    // out row for this (node, cq): bias+relu applied; bf16-packed
    uint4 ov = make_uint4(0u, 0u, 0u, 0u);
    if (e == 0 && valid) {
        uint4 sv = *(const uint4*)(hb + ((size_t)node << 7));
        accp(acc, sv);  // self-loop row (hs = dis*h)
        float dn = dis[node];
        float4 blo = *(const float4*)&bias[cq * 8];
        float4 bhi = *(const float4*)&bias[cq * 8 + 4];
        float bb[8] = {blo.x, blo.y, blo.z, blo.w, bhi.x, bhi.y, bhi.z, bhi.w};
        unsigned short o[8];
#pragma unroll
        for (int q = 0; q < 4; ++q) {
            float v0 = dn * acc[q].x + bb[2 * q + 0];
            float v1 = dn * acc[q].y + bb[2 * q + 1];
            if (RELU) {
                v0 = fmaxf(v0, 0.f);
                v1 = fmaxf(v1, 0.f);
            }
            o[2 * q + 0] = f2bf(v0);
            o[2 * q + 1] = f2bf(v1);
        }
        ov.x = (unsigned int)o[0] | ((unsigned int)o[1] << 16);
        ov.y = (unsigned int)o[2] | ((unsigned int)o[3] << 16);
        ov.z = (unsigned int)o[4] | ((unsigned int)o[5] << 16);
        ov.w = (unsigned int)o[6] | ((unsigned int)o[7] << 16);
    }

    if (FUSE) {
        if (e == 0) {
            *(uint4*)&Aout[(wv * 4 + s) * WS + cq * 8] = ov;  // zeros if !valid
        }
        __syncthreads();
        // 16x64(out) @ 64x64(Wn): wave wv computes cols [wv*16, wv*16+16)
        const int m = lane & 15, quad = lane >> 4;
        floatx4 cacc = {0.f, 0.f, 0.f, 0.f};
#pragma unroll
        for (int s2 = 0; s2 < 2; ++s2) {
            int ko = s2 * 32 + quad * 8;
            short8 a = *(const short8*)&Aout[m * WS + ko];
            short8 bf = *(const short8*)&Wt[(wv * 16 + m) * WS + ko];
            cacc = __builtin_amdgcn_mfma_f32_16x16x32_bf16(a, bf, cacc, 0, 0, 0);
        }
        int nb0 = blockIdx.x * 16;
#pragma unroll
        for (int r = 0; r < 4; ++r) {
            int nd = nb0 + quad * 4 + r;
            if (nd < N) {
                outp[(size_t)nd * 64 + wv * 16 + m] = f2bf(cacc[r] * dis[nd]);
            }
        }
    } else {
        if (e == 0 && valid) {
            *(uint4*)&outp[(size_t)node * 64 + cq * 8] = ov;
        }
    }
}

// ---------------- fused mean-pool + FC head ----------------
__global__ __launch_bounds__(256) void k_head2(const unsigned short* __restrict__ h,
                                               const int* __restrict__ batch,
                                               const float* __restrict__ Wfc,
                                               const float* __restrict__ bfc,
                                               float* __restrict__ out, int N) {
    __shared__ float part[4][64];
    __shared__ float p[64];
    int g = blockIdx.x, t = threadIdx.x;
    int w = t >> 6, lane = t & 63;
    int lo = 0, hi = N;
    while (lo < hi) { int mid = (lo + hi) >> 1; if (batch[mid] < g) lo = mid + 1; else hi = mid; }
    int s = lo;
    hi = N;
    while (lo < hi) { int mid = (lo + hi) >> 1; if (batch[mid] < g + 1) lo = mid + 1; else hi = mid; }
    int e = lo;
    float acc = 0.f;
    int n = s + w;
    for (; n + 12 < e; n += 16) {
        float a0 = bf2f(h[(size_t)(n + 0) * 64 + lane]);
        float a1 = bf2f(h[(size_t)(n + 4) * 64 + lane]);
        float a2 = bf2f(h[(size_t)(n + 8) * 64 + lane]);
        float a3 = bf2f(h[(size_t)(n + 12) * 64 + lane]);
        acc += (a0 + a1) + (a2 + a3);
    }
    for (; n < e; n += 4) acc += bf2f(h[(size_t)n * 64 + lane]);
    part[w][lane] = acc;
    __syncthreads();
    if (w == 0) {
        float a = (part[0][lane] + part[1][lane]) + (part[2][lane] + part[3][lane]);
        float cntf = (float)max(e - s, 1);
        p[lane] = a / cntf;
    }
    __syncthreads();
    if (t < 10) {
        float o = bfc[t];
#pragma unroll
        for (int hh = 0; hh < 64; ++hh) o += p[hh] * Wfc[hh * 10 + t];
        out[g * 10 + t] = o;
    }
}

extern "C" void kernel_launch(void* const* d_in, const int* in_sizes, int n_in,
                              void* d_out, int out_size, void* d_ws, size_t ws_size,
                              hipStream_t stream) {
    const float* x = (const float*)d_in[0];
    const int* eidx = (const int*)d_in[1];
    const int* batch = (const int*)d_in[2];
    const float* W1 = (const float*)d_in[3];
    const float* b1 = (const float*)d_in[4];
    const float* W2 = (const float*)d_in[5];
    const float* b2 = (const float*)d_in[6];
    const float* W3 = (const float*)d_in[7];
    const float* b3 = (const float*)d_in[8];
    const float* Wfc = (const float*)d_in[9];
    const float* bfc = (const float*)d_in[10];
    float* out = (float*)d_out;

    const int N = in_sizes[0] / 128;  // 100000
    const int E = in_sizes[1] / 2;    // 3200000
    const int G = out_size / 10;      // 512
    const int NB = (N + 255) / 256;   // 391 buckets
    const int TQ = (N + 3) / 4;       // src-tile quantum (3.2 MB of hs rows)
    int chunk = ((E + NBLK - 1) / NBLK + 3) & ~3;

    char* ws = (char*)d_ws;
    size_t off = 0;
    auto alloc = [&](size_t bytes) -> char* {
        char* p = ws + off;
        off = (off + bytes + 511) & ~(size_t)511;
        return p;
    };
    int* deg = (int*)alloc((size_t)N * 4);
    int* rowptr = (int*)alloc((size_t)N * 4);
    float* dis = (float*)alloc((size_t)N * 4);
    int* starts = (int*)alloc((size_t)(MAXNB + 1) * 4);
    int* btotal = (int*)alloc((size_t)MAXNB * 4);
    int* blockhist = (int*)alloc((size_t)NB * NBLK * 4);
    unsigned int* epart = (unsigned int*)alloc((size_t)E * 4);
    int* colidx = (int*)alloc(((size_t)E + (size_t)NB * BPAD) * 4);
    unsigned short* hsA = (unsigned short*)alloc((size_t)(N + 1) * 64 * 2);
    unsigned short* hsB = (unsigned short*)alloc((size_t)(N + 1) * 64 * 2);
    unsigned short* obufb = (unsigned short*)alloc((size_t)N * 64 * 2);

    const int* esrc = eidx;
    const int* edst = eidx + E;

    // ---- build: one cooperative kernel; fallback to 5 kernels if rejected.
    {
        int gbuild = (NB > NBLK) ? NB : NBLK;
        int Nv = N, Ev = E, chv = chunk, nbv = NB, tqv = TQ;
        void* cargs[] = {(void*)&esrc, (void*)&edst, (void*)&blockhist,
                         (void*)&btotal, (void*)&starts, (void*)&epart,
                         (void*)&deg, (void*)&rowptr, (void*)&dis,
                         (void*)&colidx, (void*)&hsA, (void*)&hsB,
                         (void*)&Nv, (void*)&Ev, (void*)&chv, (void*)&nbv,
                         (void*)&tqv};
        hipError_t cerr = hipLaunchCooperativeKernel(k_build, dim3(gbuild),
                                                     dim3(256), cargs, 0, stream);
        if (cerr != hipSuccess) {
            (void)hipGetLastError();  // clear, take non-cooperative path
            k_hist<<<NBLK, 256, 0, stream>>>(edst, blockhist, E, chunk, NB);
            k_bscan<<<NB, 256, 0, stream>>>(blockhist, btotal);
            k_sscan<<<1, 256, 0, stream>>>(btotal, starts, NB, hsA, hsB, N);
            k_part<<<NBLK, 256, 0, stream>>>(esrc, edst, blockhist, starts, epart, E, chunk, NB);
            k_fine<<<NB, 256, 0, stream>>>(epart, starts, deg, rowptr, dis, colidx, N, TQ);
        }
    }

    int gblk = (N + 63) / 64;
    int ablk = (N + 15) / 16;
    k_gemm_mfma<128, 0><<<gblk, 256, 0, stream>>>(x, W1, dis, hsA, N);
    k_agg<1, 1><<<ablk, 256, 0, stream>>>(hsA, rowptr, deg, colidx, dis, b1, W2, hsB, N);
    k_agg<1, 1><<<ablk, 256, 0, stream>>>(hsB, rowptr, deg, colidx, dis, b2, W3, hsA, N);
    k_agg<0, 0><<<ablk, 256, 0, stream>>>(hsA, rowptr, deg, colidx, dis, b3, nullptr, obufb, N);
    k_head2<<<G, 256, 0, stream>>>(obufb, batch, Wfc, bfc, out, N);
}

// Round 9
// 365.553 us; speedup vs baseline: 1.5522x; 1.5522x over previous
//
#include <hip/hip_runtime.h>
#include <hip/hip_bf16.h>

// ---------------------------------------------------------------------------
// GCN forward, 10-launch pipeline:
//   5-kernel CSR build (hist/bscan/sscan/part/fine)
//   -> gemm1 (x@W1, MFMA) -> aggF(W2) -> aggF(W3) -> agg3 -> head.
// aggF = R2-structure gather aggregate + fused 16x64 @ 64x64 MFMA epilogue
// producing the NEXT layer's hs (dis-scaled bf16) directly — gemm2/gemm3
// kernels and the obufb round-trip eliminated.
// hs = dis[n]*h[n] bf16 [N+1][64] (+zero dummy row N).
// NOTE (R5): NO float LDS atomics. (R8): don't fuse gather INTO gemm tile.
// NOTE (R10/R11): k_agg not VALU- or issue-latency-bound.
// NOTE (R12/R13/R15): spatial slabs + per-tile chains lose; k_agg wall =
// dur ~= FETCH/3.5TB/s at 1 line-req/edge with full MLP.
// NOTE (R17): COOPERATIVE BUILD FAILED: 391-block grid.sync x4 = 255us
// (VALUBusy 2%, occ 18%) vs ~45us for 5 separate kernels. Grid-wide
// barriers on 8 XCDs >> launch gaps for full-chip streaming phases.
// NOTE (R18): R8 bench was an infra failure (container), not kernel —
// identical resubmission to measure fused-epilogue + tile-ordered colidx.
// ---------------------------------------------------------------------------

#define NBLK 256        // partition chunks
#define MAXNB 512       // max buckets
#define FCAP 9216       // LDS edge staging in fine phase (36 KB)
#define BPAD 2048       // per-bucket colidx padding slack (256*7 max)
#define SMEMB (FCAP * 4 + 1024 * 4 + 1024 * 4 + 256 * 4)  // 46080 B

typedef __attribute__((ext_vector_type(8))) short short8;
typedef __attribute__((ext_vector_type(4))) float floatx4;
typedef __attribute__((ext_vector_type(2))) float f32x2;

__device__ __forceinline__ float bf2f(unsigned short v) {
    return __uint_as_float(((unsigned int)v) << 16);
}
__device__ __forceinline__ unsigned short f2bf(float x) {
    __hip_bfloat16 b = __float2bfloat16(x);
    return *(unsigned short*)&b;
}
__device__ __forceinline__ void pkacc(f32x2& a, unsigned int u) {
    f32x2 p;
    p.x = __uint_as_float(u << 16);
    p.y = __uint_as_float(u & 0xFFFF0000u);
    asm("v_pk_add_f32 %0, %1, %0" : "+v"(a) : "v"(p));
}
__device__ __forceinline__ void accp(f32x2* a, uint4 u) {
    pkacc(a[0], u.x);
    pkacc(a[1], u.y);
    pkacc(a[2], u.z);
    pkacc(a[3], u.w);
}

// P1: per-block bucket histogram (int4-vectorized edge reads). bucket = dst>>8.
__global__ __launch_bounds__(256) void k_hist(const int* __restrict__ dst,
                                              int* __restrict__ blockhist,
                                              int E, int chunk, int nb) {
    __shared__ int h[MAXNB];
    int b = blockIdx.x, t = threadIdx.x;
    for (int j = t; j < nb; j += 256) h[j] = 0;
    __syncthreads();
    int lo = b * chunk, hi = min(lo + chunk, E);
    int m = hi - lo;
    if (m < 0) m = 0;
    int nv = m >> 2;
    const int4* d4 = (const int4*)(dst + lo);
    for (int i = t; i < nv; i += 256) {
        int4 v = d4[i];
        atomicAdd(&h[v.x >> 8], 1);
        atomicAdd(&h[v.y >> 8], 1);
        atomicAdd(&h[v.z >> 8], 1);
        atomicAdd(&h[v.w >> 8], 1);
    }
    for (int i = lo + (nv << 2) + t; i < hi; i += 256) atomicAdd(&h[dst[i] >> 8], 1);
    __syncthreads();
    for (int j = t; j < nb; j += 256) blockhist[j * NBLK + b] = h[j];
}

// P2a: per-bucket exclusive scan over NBLK=256 blocks (in place); btotal[j].
__global__ __launch_bounds__(256) void k_bscan(int* __restrict__ blockhist,
                                               int* __restrict__ btotal) {
    __shared__ int sm[256];
    int j = blockIdx.x, t = threadIdx.x;
    int v = blockhist[j * NBLK + t];
    sm[t] = v;
    __syncthreads();
    for (int d = 1; d < 256; d <<= 1) {
        int u = (t >= d) ? sm[t - d] : 0;
        __syncthreads();
        sm[t] += u;
        __syncthreads();
    }
    blockhist[j * NBLK + t] = sm[t] - v;
    if (t == 255) btotal[j] = sm[255];
}

// P2b: single-block scan of bucket totals; zero dummy hs rows.
__global__ __launch_bounds__(256) void k_sscan(const int* __restrict__ btotal,
                                               int* __restrict__ starts, int nb,
                                               unsigned short* __restrict__ z1,
                                               unsigned short* __restrict__ z2,
                                               int N) {
    __shared__ int sm[256];
    int t = threadIdx.x;
    if (t < 64) {
        z1[(size_t)N * 64 + t] = 0;
        z2[(size_t)N * 64 + t] = 0;
    }
    int base = t * 2;
    int v0 = (base + 0 < nb) ? btotal[base + 0] : 0;
    int v1 = (base + 1 < nb) ? btotal[base + 1] : 0;
    int tsum = v0 + v1;
    sm[t] = tsum;
    __syncthreads();
    for (int d = 1; d < 256; d <<= 1) {
        int u = (t >= d) ? sm[t - d] : 0;
        __syncthreads();
        sm[t] += u;
        __syncthreads();
    }
    int excl = sm[t] - tsum;
    if (base + 0 < nb) starts[base + 0] = excl;
    if (base + 1 < nb) starts[base + 1] = excl + v0;
    if (t == 255) starts[nb] = sm[255];
}

// P3: partition edges into bucket regions. epart = src | (dst&255)<<17.
__global__ __launch_bounds__(256) void k_part(const int* __restrict__ src,
                                              const int* __restrict__ dst,
                                              const int* __restrict__ blockhist,
                                              const int* __restrict__ starts,
                                              unsigned int* __restrict__ epart,
                                              int E, int chunk, int nb) {
    __shared__ int cur[MAXNB];
    int b = blockIdx.x, t = threadIdx.x;
    for (int j = t; j < nb; j += 256) cur[j] = starts[j] + blockhist[j * NBLK + b];
    __syncthreads();
    int lo = b * chunk, hi = min(lo + chunk, E);
    int m = hi - lo;
    if (m < 0) m = 0;
    int nv = m >> 2;
    const int4* d4 = (const int4*)(dst + lo);
    const int4* s4 = (const int4*)(src + lo);
    for (int i = t; i < nv; i += 256) {
        int4 d = d4[i];
        int4 s = s4[i];
        int p;
        p = atomicAdd(&cur[d.x >> 8], 1); epart[p] = (unsigned int)s.x | ((unsigned int)(d.x & 255) << 17);
        p = atomicAdd(&cur[d.y >> 8], 1); epart[p] = (unsigned int)s.y | ((unsigned int)(d.y & 255) << 17);
        p = atomicAdd(&cur[d.z >> 8], 1); epart[p] = (unsigned int)s.z | ((unsigned int)(d.z & 255) << 17);
        p = atomicAdd(&cur[d.w >> 8], 1); epart[p] = (unsigned int)s.w | ((unsigned int)(d.w & 255) << 17);
    }
    for (int i = lo + (nv << 2) + t; i < hi; i += 256) {
        int d = dst[i];
        int pos = atomicAdd(&cur[d >> 8], 1);
        epart[pos] = (unsigned int)src[i] | ((unsigned int)(d & 255) << 17);
    }
}

// P4: per-bucket fine sort; per-node lists ORDERED BY SRC-TILE (4 tiles of
// TQ rows), padded to x8 with dummy row N. colidx stores byte offs (src<<7).
__global__ __launch_bounds__(256) void k_fine(const unsigned int* __restrict__ epart,
                                              const int* __restrict__ starts,
                                              int* __restrict__ deg,
                                              int* __restrict__ rowptr,
                                              float* __restrict__ dis,
                                              int* __restrict__ colidx, int N,
                                              int TQ) {
    __shared__ char smemraw[SMEMB];
    unsigned int* eb = (unsigned int*)smemraw;           // 36 KB
    int* cnt2 = (int*)(smemraw + FCAP * 4);              // [256][4]
    int* cur2 = cnt2 + 1024;
    int* sc = cur2 + 1024;
    int j = blockIdx.x, t = threadIdx.x;
    int n0 = j << 8;
    int nn = min(256, N - n0);
    int s = starts[j], e = starts[j + 1];
    int m = e - s;
    int pbase = s + j * BPAD;
    cnt2[t] = 0; cnt2[t + 256] = 0; cnt2[t + 512] = 0; cnt2[t + 768] = 0;
    __syncthreads();
    for (int i = t; i < m; i += 256) {
        unsigned int p = epart[s + i];
        if (i < FCAP) eb[i] = p;
        int tl = (int)(p & 0x1FFFF) / TQ;
        atomicAdd(&cnt2[(int)((p >> 17) << 2) + tl], 1);
    }
    __syncthreads();
    int c0 = cnt2[(t << 2) + 0], c1 = cnt2[(t << 2) + 1];
    int c2 = cnt2[(t << 2) + 2], c3 = cnt2[(t << 2) + 3];
    int cnt = c0 + c1 + c2 + c3;
    int pcv = (cnt + 7) & ~7;
    sc[t] = pcv;
    __syncthreads();
    for (int d = 1; d < 256; d <<= 1) {
        int u = (t >= d) ? sc[t - d] : 0;
        __syncthreads();
        sc[t] += u;
        __syncthreads();
    }
    int rp = pbase + sc[t] - pcv;
    if (t < nn) {
        deg[n0 + t] = cnt;
        rowptr[n0 + t] = rp;
        dis[n0 + t] = rsqrtf((float)cnt + 1.0f);
    }
    cur2[(t << 2) + 0] = rp;
    cur2[(t << 2) + 1] = rp + c0;
    cur2[(t << 2) + 2] = rp + c0 + c1;
    cur2[(t << 2) + 3] = rp + c0 + c1 + c2;
    __syncthreads();
    for (int i = t; i < m; i += 256) {
        unsigned int p = (i < FCAP) ? eb[i] : epart[s + i];
        int srcn = (int)(p & 0x1FFFF);
        int tl = srcn / TQ;
        int pos = atomicAdd(&cur2[(int)((p >> 17) << 2) + tl], 1);
        colidx[pos] = srcn << 7;
    }
    __syncthreads();
    if (t < nn) {
        int endp = rp + pcv;
        for (int q = rp + cnt; q < endp; ++q) colidx[q] = N << 7;  // dummy row
    }
}

// ---------------- layer-1 GEMM (fp32 A, K=128) ----------------
template <int K, int ABF16>
__global__ __launch_bounds__(256) void k_gemm_mfma(const void* __restrict__ Ap,
                                                   const float* __restrict__ W,
                                                   const float* __restrict__ dis,
                                                   unsigned short* __restrict__ hs,
                                                   int N) {
    constexpr int AS = K + 8;
    __shared__ unsigned short As[64 * AS];
    __shared__ unsigned short Bt[64 * AS];
    const int tid = threadIdx.x;
    const int r0 = blockIdx.x * 64;

    for (int idx = tid; idx < K * 64; idx += 256) {
        int k = idx >> 6, n = idx & 63;
        Bt[n * AS + k] = f2bf(W[idx]);
    }
    if (ABF16) {
        const unsigned short* A = (const unsigned short*)Ap;
        for (int idx = tid; idx < 64 * (K / 8); idx += 256) {
            int row = idx / (K / 8), c8 = idx % (K / 8);
            int gr = r0 + row;
            uint4 v = (gr < N) ? *(const uint4*)&A[(size_t)gr * K + c8 * 8]
                               : make_uint4(0u, 0u, 0u, 0u);
            *(uint4*)&As[row * AS + c8 * 8] = v;
        }
    } else {
        const float* A = (const float*)Ap;
        for (int idx = tid; idx < 64 * (K / 4); idx += 256) {
            int row = idx / (K / 4), kq = idx % (K / 4);
            int gr = r0 + row;
            float4 a = (gr < N) ? ((const float4*)(A + (size_t)gr * K))[kq]
                                : make_float4(0.f, 0.f, 0.f, 0.f);
            ushort4 v;
            v.x = f2bf(a.x); v.y = f2bf(a.y); v.z = f2bf(a.z); v.w = f2bf(a.w);
            *(ushort4*)&As[row * AS + kq * 4] = v;
        }
    }
    __syncthreads();

    const int w = tid >> 6, lane = tid & 63;
    const int m = lane & 15, quad = lane >> 4;
    floatx4 acc0 = {0.f, 0.f, 0.f, 0.f};
    floatx4 acc1 = {0.f, 0.f, 0.f, 0.f};
    floatx4 acc2 = {0.f, 0.f, 0.f, 0.f};
    floatx4 acc3 = {0.f, 0.f, 0.f, 0.f};
#pragma unroll
    for (int s = 0; s < K / 32; ++s) {
        int ko = s * 32 + quad * 8;
        short8 a  = *(const short8*)&As[(w * 16 + m) * AS + ko];
        short8 b0 = *(const short8*)&Bt[(0 * 16 + m) * AS + ko];
        short8 b1 = *(const short8*)&Bt[(1 * 16 + m) * AS + ko];
        short8 b2 = *(const short8*)&Bt[(2 * 16 + m) * AS + ko];
        short8 b3 = *(const short8*)&Bt[(3 * 16 + m) * AS + ko];
        acc0 = __builtin_amdgcn_mfma_f32_16x16x32_bf16(a, b0, acc0, 0, 0, 0);
        acc1 = __builtin_amdgcn_mfma_f32_16x16x32_bf16(a, b1, acc1, 0, 0, 0);
        acc2 = __builtin_amdgcn_mfma_f32_16x16x32_bf16(a, b2, acc2, 0, 0, 0);
        acc3 = __builtin_amdgcn_mfma_f32_16x16x32_bf16(a, b3, acc3, 0, 0, 0);
    }
#pragma unroll
    for (int r = 0; r < 4; ++r) {
        int gr = r0 + w * 16 + quad * 4 + r;
        if (gr < N) {
            float dn = dis[gr];
            size_t base = (size_t)gr * 64 + m;
            hs[base + 0]  = f2bf(acc0[r] * dn);
            hs[base + 16] = f2bf(acc1[r] * dn);
            hs[base + 32] = f2bf(acc2[r] * dn);
            hs[base + 48] = f2bf(acc3[r] * dn);
        }
    }
}

// ---------------- gather aggregate (+ optional fused next-layer GEMM) ------
// R2 structure: 4 nodes/wave, lane = slot(2b) x eslot-parity(1b) x cq(3b),
// 2-deep pipeline, 1-level butterfly. FUSE: stage 16x64 bf16 out-tile in
// LDS, compute hs_next = dis * (out @ Wn) via 2x 16x16x32 MFMA per wave.
template <int RELU, int FUSE>
__global__ __launch_bounds__(256) void k_agg(const unsigned short* __restrict__ hs,
                                             const int* __restrict__ rowptr,
                                             const int* __restrict__ deg,
                                             const int* __restrict__ colidx,
                                             const float* __restrict__ dis,
                                             const float* __restrict__ bias,
                                             const float* __restrict__ Wn,
                                             unsigned short* __restrict__ outp,
                                             int N) {
    constexpr int WS = 72;
    __shared__ unsigned short Wt[FUSE ? 64 * WS : 1];
    __shared__ unsigned short Aout[FUSE ? 16 * WS : 1];

    int lane = threadIdx.x & 63;
    int wv = threadIdx.x >> 6;
    int s = lane >> 4;          // node slot 0..3
    int e = (lane >> 3) & 1;    // edge-slot parity
    int cq = lane & 7;          // channel octet
    int node = blockIdx.x * 16 + wv * 4 + s;
    bool valid = node < N;
    int nodec = valid ? node : 0;

    if (FUSE) {
        for (int idx = threadIdx.x; idx < 64 * 64; idx += 256) {
            int k = idx >> 6, c = idx & 63;
            Wt[c * WS + k] = f2bf(Wn[idx]);
        }
        // visibility via the __syncthreads before the matmul
    }

    int rp = rowptr[nodec];
    int cnt = valid ? deg[nodec] : 0;
    int pcnt = (cnt + 7) & ~7;
    int wm = pcnt;
    wm = max(wm, __shfl_xor(wm, 16, 64));
    wm = max(wm, __shfl_xor(wm, 32, 64));

    const int* ci = colidx + rp + e;
    const char* hb = (const char*)hs + cq * 16;
    const int DUMMY = N << 7;
    const int mclamp = max(pcnt - 2, 0);

    f32x2 acc[4];
    acc[0] = (f32x2){0.f, 0.f};
    acc[1] = (f32x2){0.f, 0.f};
    acc[2] = (f32x2){0.f, 0.f};
    acc[3] = (f32x2){0.f, 0.f};

    auto LDO = [&](int i, int& o0, int& o1) {
        int r0 = ci[min(i, mclamp)];
        int r1 = ci[min(i + 2, mclamp)];
        o0 = (i + e < pcnt) ? r0 : DUMMY;
        o1 = (i + 2 + e < pcnt) ? r1 : DUMMY;
    };

    if (wm > 0) {
        int a0, a1, b0, b1;
        LDO(0, a0, a1);
        LDO(4, b0, b1);
        uint4 gA0 = *(const uint4*)(hb + a0);
        uint4 gA1 = *(const uint4*)(hb + a1);
        uint4 gB0 = *(const uint4*)(hb + b0);
        uint4 gB1 = *(const uint4*)(hb + b1);
        for (int i = 8; i < wm; i += 8) {
            int c0, c1, d0, d1;
            LDO(i, c0, c1);
            LDO(i + 4, d0, d1);
            accp(acc, gA0);
            accp(acc, gA1);
            gA0 = *(const uint4*)(hb + c0);
            gA1 = *(const uint4*)(hb + c1);
            accp(acc, gB0);
            accp(acc, gB1);
            gB0 = *(const uint4*)(hb + d0);
            gB1 = *(const uint4*)(hb + d1);
        }
        accp(acc, gA0);
        accp(acc, gA1);
        accp(acc, gB0);
        accp(acc, gB1);
    }

#pragma unroll
    for (int q = 0; q < 4; ++q) {
        f32x2 t;
        t.x = __shfl_xor(acc[q].x, 8, 64);
        t.y = __shfl_xor(acc[q].y, 8, 64);
        asm("v_pk_add_f32 %0, %1, %0" : "+v"(acc[q]) : "v"(t));
    }

    uint4 ov = make_uint4(0u, 0u, 0u, 0u);
    if (e == 0 && valid) {
        uint4 sv = *(const uint4*)(hb + ((size_t)node << 7));
        accp(acc, sv);  // self-loop row (hs = dis*h)
        float dn = dis[node];
        float4 blo = *(const float4*)&bias[cq * 8];
        float4 bhi = *(const float4*)&bias[cq * 8 + 4];
        float bb[8] = {blo.x, blo.y, blo.z, blo.w, bhi.x, bhi.y, bhi.z, bhi.w};
        unsigned short o[8];
#pragma unroll
        for (int q = 0; q < 4; ++q) {
            float v0 = dn * acc[q].x + bb[2 * q + 0];
            float v1 = dn * acc[q].y + bb[2 * q + 1];
            if (RELU) {
                v0 = fmaxf(v0, 0.f);
                v1 = fmaxf(v1, 0.f);
            }
            o[2 * q + 0] = f2bf(v0);
            o[2 * q + 1] = f2bf(v1);
        }
        ov.x = (unsigned int)o[0] | ((unsigned int)o[1] << 16);
        ov.y = (unsigned int)o[2] | ((unsigned int)o[3] << 16);
        ov.z = (unsigned int)o[4] | ((unsigned int)o[5] << 16);
        ov.w = (unsigned int)o[6] | ((unsigned int)o[7] << 16);
    }

    if (FUSE) {
        if (e == 0) {
            *(uint4*)&Aout[(wv * 4 + s) * WS + cq * 8] = ov;  // zeros if !valid
        }
        __syncthreads();
        // 16x64(out) @ 64x64(Wn): wave wv computes cols [wv*16, wv*16+16)
        const int m = lane & 15, quad = lane >> 4;
        floatx4 cacc = {0.f, 0.f, 0.f, 0.f};
#pragma unroll
        for (int s2 = 0; s2 < 2; ++s2) {
            int ko = s2 * 32 + quad * 8;
            short8 a = *(const short8*)&Aout[m * WS + ko];
            short8 bf = *(const short8*)&Wt[(wv * 16 + m) * WS + ko];
            cacc = __builtin_amdgcn_mfma_f32_16x16x32_bf16(a, bf, cacc, 0, 0, 0);
        }
        int nb0 = blockIdx.x * 16;
#pragma unroll
        for (int r = 0; r < 4; ++r) {
            int nd = nb0 + quad * 4 + r;
            if (nd < N) {
                outp[(size_t)nd * 64 + wv * 16 + m] = f2bf(cacc[r] * dis[nd]);
            }
        }
    } else {
        if (e == 0 && valid) {
            *(uint4*)&outp[(size_t)node * 64 + cq * 8] = ov;
        }
    }
}

// ---------------- fused mean-pool + FC head ----------------
__global__ __launch_bounds__(256) void k_head2(const unsigned short* __restrict__ h,
                                               const int* __restrict__ batch,
                                               const float* __restrict__ Wfc,
                                               const float* __restrict__ bfc,
                                               float* __restrict__ out, int N) {
    __shared__ float part[4][64];
    __shared__ float p[64];
    int g = blockIdx.x, t = threadIdx.x;
    int w = t >> 6, lane = t & 63;
    int lo = 0, hi = N;
    while (lo < hi) { int mid = (lo + hi) >> 1; if (batch[mid] < g) lo = mid + 1; else hi = mid; }
    int s = lo;
    hi = N;
    while (lo < hi) { int mid = (lo + hi) >> 1; if (batch[mid] < g + 1) lo = mid + 1; else hi = mid; }
    int e = lo;
    float acc = 0.f;
    int n = s + w;
    for (; n + 12 < e; n += 16) {
        float a0 = bf2f(h[(size_t)(n + 0) * 64 + lane]);
        float a1 = bf2f(h[(size_t)(n + 4) * 64 + lane]);
        float a2 = bf2f(h[(size_t)(n + 8) * 64 + lane]);
        float a3 = bf2f(h[(size_t)(n + 12) * 64 + lane]);
        acc += (a0 + a1) + (a2 + a3);
    }
    for (; n < e; n += 4) acc += bf2f(h[(size_t)n * 64 + lane]);
    part[w][lane] = acc;
    __syncthreads();
    if (w == 0) {
        float a = (part[0][lane] + part[1][lane]) + (part[2][lane] + part[3][lane]);
        float cntf = (float)max(e - s, 1);
        p[lane] = a / cntf;
    }
    __syncthreads();
    if (t < 10) {
        float o = bfc[t];
#pragma unroll
        for (int hh = 0; hh < 64; ++hh) o += p[hh] * Wfc[hh * 10 + t];
        out[g * 10 + t] = o;
    }
}

extern "C" void kernel_launch(void* const* d_in, const int* in_sizes, int n_in,
                              void* d_out, int out_size, void* d_ws, size_t ws_size,
                              hipStream_t stream) {
    const float* x = (const float*)d_in[0];
    const int* eidx = (const int*)d_in[1];
    const int* batch = (const int*)d_in[2];
    const float* W1 = (const float*)d_in[3];
    const float* b1 = (const float*)d_in[4];
    const float* W2 = (const float*)d_in[5];
    const float* b2 = (const float*)d_in[6];
    const float* W3 = (const float*)d_in[7];
    const float* b3 = (const float*)d_in[8];
    const float* Wfc = (const float*)d_in[9];
    const float* bfc = (const float*)d_in[10];
    float* out = (float*)d_out;

    const int N = in_sizes[0] / 128;  // 100000
    const int E = in_sizes[1] / 2;    // 3200000
    const int G = out_size / 10;      // 512
    const int NB = (N + 255) / 256;   // 391 buckets
    const int TQ = (N + 3) / 4;       // src-tile quantum (3.2 MB of hs rows)
    int chunk = ((E + NBLK - 1) / NBLK + 3) & ~3;

    char* ws = (char*)d_ws;
    size_t off = 0;
    auto alloc = [&](size_t bytes) -> char* {
        char* p = ws + off;
        off = (off + bytes + 511) & ~(size_t)511;
        return p;
    };
    int* deg = (int*)alloc((size_t)N * 4);
    int* rowptr = (int*)alloc((size_t)N * 4);
    float* dis = (float*)alloc((size_t)N * 4);
    int* starts = (int*)alloc((size_t)(MAXNB + 1) * 4);
    int* btotal = (int*)alloc((size_t)MAXNB * 4);
    int* blockhist = (int*)alloc((size_t)NB * NBLK * 4);
    unsigned int* epart = (unsigned int*)alloc((size_t)E * 4);
    int* colidx = (int*)alloc(((size_t)E + (size_t)NB * BPAD) * 4);
    unsigned short* hsA = (unsigned short*)alloc((size_t)(N + 1) * 64 * 2);
    unsigned short* hsB = (unsigned short*)alloc((size_t)(N + 1) * 64 * 2);
    unsigned short* obufb = (unsigned short*)alloc((size_t)N * 64 * 2);

    const int* esrc = eidx;
    const int* edst = eidx + E;

    k_hist<<<NBLK, 256, 0, stream>>>(edst, blockhist, E, chunk, NB);
    k_bscan<<<NB, 256, 0, stream>>>(blockhist, btotal);
    k_sscan<<<1, 256, 0, stream>>>(btotal, starts, NB, hsA, hsB, N);
    k_part<<<NBLK, 256, 0, stream>>>(esrc, edst, blockhist, starts, epart, E, chunk, NB);
    k_fine<<<NB, 256, 0, stream>>>(epart, starts, deg, rowptr, dis, colidx, N, TQ);

    int gblk = (N + 63) / 64;
    int ablk = (N + 15) / 16;
    k_gemm_mfma<128, 0><<<gblk, 256, 0, stream>>>(x, W1, dis, hsA, N);
    k_agg<1, 1><<<ablk, 256, 0, stream>>>(hsA, rowptr, deg, colidx, dis, b1, W2, hsB, N);
    k_agg<1, 1><<<ablk, 256, 0, stream>>>(hsB, rowptr, deg, colidx, dis, b2, W3, hsA, N);
    k_agg<0, 0><<<ablk, 256, 0, stream>>>(hsA, rowptr, deg, colidx, dis, b3, nullptr, obufb, N);
    k_head2<<<G, 256, 0, stream>>>(obufb, batch, Wfc, bfc, out, N);
}